// Round 5
// baseline (740.528 us; speedup 1.0000x reference)
//
#include <hip/hip_runtime.h>

// ---------------------------------------------------------------------------
// MultiModalRelationGraph — R5
// - L1/L2 GEMM: BARRIER-FREE. A and B both pre-packed in MFMA fragment order;
//   all operands load global->VGPR as coalesced 1KB dwordx4 (L2-resident).
//   No LDS, no __syncthreads -> no vmcnt(0) barrier drain (the m97 plateau
//   that capped R2/R4 at ~30% MfmaUtil).
// - A-packing is FREE: the agg kernels write x in fragment order (same store
//   count, 8B aligned granules); agg block-ID swizzle puts the 16 blocks of
//   one 128B sector on one XCD for L2 write-combining.
// - L0 GEMM + proj keep the R4 LDS path (row-major x0).
// - Alphas inside agg (R3), packed-B (R4), XCD swizzle + XOR LDS swizzle (R2).
// Node layout: region i in [i*8192,(i+1)*8192), node = i*8192 + b*512 + t.
// Audio: 32768 + b*1024 + ta.  Packed x: frag=(mt*32+kb), elem q*16+r, j.
// ---------------------------------------------------------------------------

typedef unsigned short u16;
typedef unsigned int u32;
typedef __bf16 bf16x8 __attribute__((ext_vector_type(8)));
typedef float f32x4 __attribute__((ext_vector_type(4)));

#define ASYNC16(gp, lp)                                                        \
  __builtin_amdgcn_global_load_lds(                                            \
      (const __attribute__((address_space(1))) void*)(gp),                     \
      (__attribute__((address_space(3))) void*)(lp), 16, 0, 0)

__device__ __forceinline__ u16 f2bf(float f) {
  union { float f; u32 u; } v; v.f = f;
  u32 u = v.u + 0x7FFFu + ((v.u >> 16) & 1u);  // RNE
  return (u16)(u >> 16);
}
__device__ __forceinline__ float bf2f(u16 x) {
  union { u32 u; float f; } v; v.u = ((u32)x) << 16;
  return v.f;
}
__device__ __forceinline__ float4 load_bf4(const u16* p) {
  ushort4 s = *(const ushort4*)p;
  float4 r; r.x = bf2f(s.x); r.y = bf2f(s.y); r.z = bf2f(s.z); r.w = bf2f(s.w);
  return r;
}
__device__ __forceinline__ float lrelu(float v) { return v > 0.f ? v : 0.2f * v; }
__device__ __forceinline__ float dot4(float4 a, float4 b) {
  return a.x * b.x + a.y * b.y + a.z * b.z + a.w * b.w;
}
__device__ __forceinline__ float wred(float v) {  // lane 0 valid
#pragma unroll
  for (int off = 32; off; off >>= 1) v += __shfl_down(v, off);
  return v;
}
__device__ __forceinline__ float wredx(float v) {  // all lanes valid
#pragma unroll
  for (int off = 32; off; off >>= 1) v += __shfl_xor(v, off);
  return v;
}

// ---------------- weight pack: W [K][N] fp32 -> MFMA B-fragment order -------
struct PK { const float* W[8]; u16* P[8]; int KB[8]; int NN[8]; int st[9]; };
__global__ __launch_bounds__(256) void pack_kernel(PK p) {
  const int f = blockIdx.x * 4 + (threadIdx.x >> 6);
  const int lane = threadIdx.x & 63;
  int e = 0;
  while (f >= p.st[e + 1]) ++e;
  const int local = f - p.st[e];
  const int KB = p.KB[e], N = p.NN[e];
  const int nt = local / KB, kb = local % KB;
  const float* W = p.W[e] + (size_t)(kb * 32 + (lane >> 4) * 8) * N + nt * 16 + (lane & 15);
  u16* dst = p.P[e] + ((size_t)local * 64 + lane) * 8;
  u16 o[8];
#pragma unroll
  for (int j = 0; j < 8; ++j) o[j] = f2bf(W[(size_t)j * N]);
  *(uint4*)dst = *(uint4*)o;
}

// ---------------- L1/L2 GEMM: barrier-free, A+B fragment-packed -------------
// C[M,1024] = A @ W^T, K=1024 (KB=32). grid (8,384), XCD swizzle.
__global__ __launch_bounds__(256) void gemm_packed_kernel(
    const u16* __restrict__ Ap, const u16* __restrict__ Bp, u16* __restrict__ C) {
  const int KB = 32;
  const int w = blockIdx.y * 8 + blockIdx.x;
  const int xcd = w & 7, m = w >> 3;
  const int blockCol = (m & 7) * 128;
  const int blockRow = ((m >> 3) * 8 + xcd) * 128;
  const int tid = threadIdx.x;
  const int wave = tid >> 6, lane = tid & 63;
  const int wr = (wave >> 1) * 64, wc = (wave & 1) * 64;
  const int lr = lane & 15, lq = lane >> 4;

  const u16* Ab[4];
  const u16* Bb[4];
#pragma unroll
  for (int mi = 0; mi < 4; ++mi) {
    const int mt = ((blockRow + wr) >> 4) + mi;
    Ab[mi] = Ap + ((size_t)mt * KB * 64 + lane) * 8;
  }
#pragma unroll
  for (int ni = 0; ni < 4; ++ni) {
    const int nt = ((blockCol + wc) >> 4) + ni;
    Bb[ni] = Bp + ((size_t)nt * KB * 64 + lane) * 8;
  }

  f32x4 acc[4][4] = {};

#pragma unroll 2
  for (int kb = 0; kb < KB; ++kb) {
    bf16x8 af[4], bfr[4];
#pragma unroll
    for (int mi = 0; mi < 4; ++mi)
      af[mi] = *(const bf16x8*)(Ab[mi] + kb * 512);
#pragma unroll
    for (int ni = 0; ni < 4; ++ni)
      bfr[ni] = *(const bf16x8*)(Bb[ni] + kb * 512);
#pragma unroll
    for (int mi = 0; mi < 4; ++mi)
#pragma unroll
      for (int ni = 0; ni < 4; ++ni)
        acc[mi][ni] = __builtin_amdgcn_mfma_f32_16x16x32_bf16(af[mi], bfr[ni],
                                                              acc[mi][ni], 0, 0, 0);
  }
  // C/D layout: col=lane&15, row=(lane>>4)*4+reg [m89/m91]; h row-major.
#pragma unroll
  for (int mi = 0; mi < 4; ++mi)
#pragma unroll
    for (int ni = 0; ni < 4; ++ni) {
      const int col = blockCol + wc + ni * 16 + lr;
#pragma unroll
      for (int r = 0; r < 4; ++r) {
        const int row = blockRow + wr + mi * 16 + lq * 4 + r;
        C[(size_t)row * 1024 + col] = f2bf(acc[mi][ni][r]);
      }
    }
}

// ---------------- L0 GEMM: LDS-staged A (row-major), packed B (R4) ----------
__global__ __launch_bounds__(256) void gemm_kernel(
    const u16* __restrict__ A, const u16* __restrict__ Bp, u16* __restrict__ C,
    int K, int ldc) {
  __shared__ __align__(16) u16 As[128 * 32];
  const int KB = K >> 5;
  const int w = blockIdx.y * 8 + blockIdx.x;
  const int xcd = w & 7, m = w >> 3;
  const int blockCol = (m & 7) * 128;
  const int blockRow = ((m >> 3) * 8 + xcd) * 128;
  const int tid = threadIdx.x;
  const int wave = tid >> 6, lane = tid & 63;
  const int wr = (wave >> 1) * 64, wc = (wave & 1) * 64;
  const int lr = lane & 15, lq = lane >> 4;
  const int sRow = wave * 16 + (lane >> 2);
  const int sGc = (lane & 3) ^ ((sRow >> 1) & 3);
  const size_t aOff0 = (size_t)(blockRow + sRow) * K + sGc * 8;
  const size_t aOff1 = aOff0 + (size_t)64 * K;
  u16* asb0 = As + wave * 512;
  u16* asb1 = As + 2048 + wave * 512;

  const u16* Bn[4];
#pragma unroll
  for (int ni = 0; ni < 4; ++ni)
    Bn[ni] = Bp + ((size_t)(((blockCol + wc) >> 4) + ni) * KB) * 512 + lane * 8;

  f32x4 acc[4][4] = {};

  for (int k0 = 0; k0 < K; k0 += 32) {
    __syncthreads();
    ASYNC16(A + aOff0 + k0, asb0);
    ASYNC16(A + aOff1 + k0, asb1);
    bf16x8 bfr[4];
#pragma unroll
    for (int ni = 0; ni < 4; ++ni)
      bfr[ni] = *(const bf16x8*)(Bn[ni] + (size_t)k0 * 16);
    __syncthreads();
    bf16x8 af[4];
#pragma unroll
    for (int mi = 0; mi < 4; ++mi) {
      const int R = wr + mi * 16 + lr;
      const int cp = lq ^ ((R >> 1) & 3);
      af[mi] = *(const bf16x8*)(&As[R * 32 + cp * 8]);
    }
#pragma unroll
    for (int mi = 0; mi < 4; ++mi)
#pragma unroll
      for (int ni = 0; ni < 4; ++ni)
        acc[mi][ni] = __builtin_amdgcn_mfma_f32_16x16x32_bf16(af[mi], bfr[ni],
                                                              acc[mi][ni], 0, 0, 0);
  }
#pragma unroll
  for (int mi = 0; mi < 4; ++mi)
#pragma unroll
    for (int ni = 0; ni < 4; ++ni) {
      const int col = blockCol + wc + ni * 16 + lr;
#pragma unroll
      for (int r = 0; r < 4; ++r) {
        const int row = blockRow + wr + mi * 16 + lq * 4 + r;
        C[(size_t)row * ldc + col] = f2bf(acc[mi][ni][r]);
      }
    }
}

// ---------------- fused input projection (fp32 A in-register cvt) -----------
struct ProjArgs { const float* x[5]; const u16* w[5]; const float* b[5]; };
__global__ __launch_bounds__(256) void proj_kernel(ProjArgs pa,
                                                   u16* __restrict__ C) {
  __shared__ __align__(16) u16 As[128 * 32];
  const int blockRow = blockIdx.y * 128, blockCol = blockIdx.x * 128;
  const int reg = blockRow >= 32768 ? 4 : (blockRow >> 13);
  const int regBase = reg == 4 ? 32768 : reg * 8192;
  const float* Af = pa.x[reg] + (size_t)(blockRow - regBase) * 512;
  const u16* Bp = pa.w[reg];
  const int tid = threadIdx.x;
  const int wave = tid >> 6, lane = tid & 63;
  const int wr = (wave >> 1) * 64, wc = (wave & 1) * 64;
  const int lr = lane & 15, lq = lane >> 4;
  const int rr = tid >> 2;
  const int cphys = tid & 3;
  const int sGc = cphys ^ ((tid >> 3) & 3);

  const u16* Bn[4];
#pragma unroll
  for (int ni = 0; ni < 4; ++ni)
    Bn[ni] = Bp + ((size_t)(((blockCol + wc) >> 4) + ni) * 16) * 512 + lane * 8;

  f32x4 acc[4][4] = {};

  for (int k0 = 0; k0 < 512; k0 += 32) {
    __syncthreads();
    bf16x8 bfr[4];
#pragma unroll
    for (int ni = 0; ni < 4; ++ni)
      bfr[ni] = *(const bf16x8*)(Bn[ni] + (size_t)k0 * 16);
#pragma unroll
    for (int i = 0; i < 2; ++i) {
      const int row = i * 64 + rr;
      const float* ap = Af + (size_t)row * 512 + k0 + sGc * 8;
      float4 f0 = *(const float4*)(ap);
      float4 f1 = *(const float4*)(ap + 4);
      uint4 pk;
      pk.x = (u32)f2bf(f0.x) | ((u32)f2bf(f0.y) << 16);
      pk.y = (u32)f2bf(f0.z) | ((u32)f2bf(f0.w) << 16);
      pk.z = (u32)f2bf(f1.x) | ((u32)f2bf(f1.y) << 16);
      pk.w = (u32)f2bf(f1.z) | ((u32)f2bf(f1.w) << 16);
      *(uint4*)(&As[row * 32 + cphys * 8]) = pk;
    }
    __syncthreads();
    bf16x8 af[4];
#pragma unroll
    for (int mi = 0; mi < 4; ++mi) {
      const int R = wr + mi * 16 + lr;
      const int cp = lq ^ ((R >> 1) & 3);
      af[mi] = *(const bf16x8*)(&As[R * 32 + cp * 8]);
    }
#pragma unroll
    for (int mi = 0; mi < 4; ++mi)
#pragma unroll
      for (int ni = 0; ni < 4; ++ni)
        acc[mi][ni] = __builtin_amdgcn_mfma_f32_16x16x32_bf16(af[mi], bfr[ni],
                                                              acc[mi][ni], 0, 0, 0);
  }
  const float* bias = pa.b[reg];
#pragma unroll
  for (int mi = 0; mi < 4; ++mi)
#pragma unroll
    for (int ni = 0; ni < 4; ++ni) {
      const int col = blockCol + wc + ni * 16 + lr;
      const float bv = bias[col];
#pragma unroll
      for (int r = 0; r < 4; ++r) {
        const int row = blockRow + wr + mi * 16 + lq * 4 + r;
        C[(size_t)row * 256 + col] = f2bf(acc[mi][ni][r] + bv);
      }
    }
}

// ---------------- fused aggregation: region + audio -------------------------
// !MEAN: writes x in A-fragment-packed order (KB=32) for the barrier-free
// GEMM. Block-ID swizzle: the 16 blocks (r=0..15) filling one 128B packed
// sector get IDs differing by 8 -> same XCD (round-robin heuristic) -> L2
// write-combining. MEAN: row-major fp32 out.
template <bool MEAN>
__global__ __launch_bounds__(256) void agg_kernel(
    const u16* __restrict__ h, const float* __restrict__ a_s,
    const float* __restrict__ a_d, const float* __restrict__ bias,
    void* __restrict__ out) {
  const int tid = threadIdx.x;
  const int head = tid >> 6, lane = tid & 63;
  const int c4 = tid * 4;
  const float4 sa = *(const float4*)(a_s + c4);
  const float4 da = *(const float4*)(a_d + c4);
  const int kb = c4 >> 5, q = (c4 >> 3) & 3, j0 = c4 & 7;  // packed coords
  __shared__ float asL[4][4], adL[4][4], apL[4][4];
  __shared__ float alpha[4][4][5];

  if (blockIdx.x < 8192) {
    const int id = blockIdx.x;
    const int bt = ((id & 7) << 10) | (id >> 3);  // bijective XCD-sector swizzle
    const int t = bt & 511;
    const bool hasPrev = t > 0;
    float4 hv[4], hp[4];
#pragma unroll
    for (int r = 0; r < 4; ++r)
      hv[r] = load_bf4(h + (size_t)(r * 8192 + bt) * 1024 + c4);
    if (hasPrev) {
#pragma unroll
      for (int r = 0; r < 4; ++r)
        hp[r] = load_bf4(h + (size_t)(r * 8192 + bt - 1) * 1024 + c4);
    }
#pragma unroll
    for (int r = 0; r < 4; ++r) {
      float ss = wred(dot4(hv[r], sa));
      float dd = wred(dot4(hv[r], da));
      float sp = hasPrev ? wred(dot4(hp[r], sa)) : 0.f;
      if (lane == 0) { asL[r][head] = ss; adL[r][head] = dd; apL[r][head] = sp; }
    }
    __syncthreads();
    if (tid < 16) {
      const int j = tid >> 2, hh = tid & 3;
      const float ad = adL[j][hh];
      float e[5];
#pragma unroll
      for (int r = 0; r < 4; ++r) e[r] = lrelu(asL[r][hh] + ad);
      int cnt = 4;
      if (hasPrev) { e[4] = lrelu(apL[j][hh] + ad); cnt = 5; }
      float mx = e[0];
      for (int k = 1; k < cnt; ++k) mx = fmaxf(mx, e[k]);
      float s = 0.f, ex[5];
      for (int k = 0; k < cnt; ++k) { ex[k] = __expf(e[k] - mx); s += ex[k]; }
      const float inv = 1.f / (s + 1e-16f);
#pragma unroll
      for (int k = 0; k < 5; ++k) alpha[j][hh][k] = (k < cnt) ? ex[k] * inv : 0.f;
    }
    __syncthreads();
    if constexpr (!MEAN) {
      const float4 bv = *(const float4*)(bias + c4);
      u16* ob = (u16*)out;
      const int r = bt & 15;
#pragma unroll
      for (int j = 0; j < 4; ++j) {
        const float* al = &alpha[j][head][0];
        float4 acc;
        acc.x = al[0] * hv[0].x + al[1] * hv[1].x + al[2] * hv[2].x + al[3] * hv[3].x;
        acc.y = al[0] * hv[0].y + al[1] * hv[1].y + al[2] * hv[2].y + al[3] * hv[3].y;
        acc.z = al[0] * hv[0].z + al[1] * hv[1].z + al[2] * hv[2].z + al[3] * hv[3].z;
        acc.w = al[0] * hv[0].w + al[1] * hv[1].w + al[2] * hv[2].w + al[3] * hv[3].w;
        if (hasPrev) {
          const float a4 = al[4];
          acc.x += a4 * hp[j].x; acc.y += a4 * hp[j].y;
          acc.z += a4 * hp[j].z; acc.w += a4 * hp[j].w;
        }
        ushort4 o;
        o.x = f2bf(acc.x + bv.x); o.y = f2bf(acc.y + bv.y);
        o.z = f2bf(acc.z + bv.z); o.w = f2bf(acc.w + bv.w);
        const int mt = j * 512 + (bt >> 4);
        *(ushort4*)(ob + (((size_t)(mt * 32 + kb) * 64 + q * 16 + r) * 8 + j0)) = o;
      }
    } else {
      __shared__ float red[4][1024];
#pragma unroll
      for (int j = 0; j < 4; ++j) {
        const float* al = &alpha[j][head][0];
        float4 acc;
        acc.x = al[0] * hv[0].x + al[1] * hv[1].x + al[2] * hv[2].x + al[3] * hv[3].x;
        acc.y = al[0] * hv[0].y + al[1] * hv[1].y + al[2] * hv[2].y + al[3] * hv[3].y;
        acc.z = al[0] * hv[0].z + al[1] * hv[1].z + al[2] * hv[2].z + al[3] * hv[3].z;
        acc.w = al[0] * hv[0].w + al[1] * hv[1].w + al[2] * hv[2].w + al[3] * hv[3].w;
        if (hasPrev) {
          const float a4 = al[4];
          acc.x += a4 * hp[j].x; acc.y += a4 * hp[j].y;
          acc.z += a4 * hp[j].z; acc.w += a4 * hp[j].w;
        }
        *(float4*)(&red[j][c4]) = acc;
      }
      __syncthreads();
      const float bb = bias[tid];
      float* of = (float*)out;
#pragma unroll
      for (int j = 0; j < 4; ++j)
        of[(size_t)(j * 8192 + bt) * 256 + tid] =
            0.25f * (red[j][tid] + red[j][tid + 256] + red[j][tid + 512] +
                     red[j][tid + 768]) + bb;
    }
  } else {
    const int aid = blockIdx.x - 8192;
    const int idx = ((aid & 7) << 11) | (aid >> 3);  // bijective swizzle
    const int ta = idx & 1023;
    const int node = 32768 + idx;
    const bool even = ((ta & 1) == 0);
    float4 v = load_bf4(h + (size_t)node * 1024 + c4);
    if (even) {
      const int b = idx >> 10;
      const int tt = ta >> 1;
      const int le = 8192 + b * 512 + tt;
      const int re = 16384 + b * 512 + tt;
      float4 v1 = load_bf4(h + (size_t)le * 1024 + c4);
      float4 v2 = load_bf4(h + (size_t)re * 1024 + c4);
      float s0 = wred(dot4(v, sa));
      float s1 = wred(dot4(v1, sa));
      float s2 = wred(dot4(v2, sa));
      float d0 = wred(dot4(v, da));
      if (lane == 0) {
        asL[0][head] = s0; asL[1][head] = s1; asL[2][head] = s2; adL[0][head] = d0;
      }
      __syncthreads();
      if (tid < 4) {
        const float ad = adL[0][tid];
        float e0 = lrelu(asL[0][tid] + ad);
        float e1 = lrelu(asL[1][tid] + ad);
        float e2 = lrelu(asL[2][tid] + ad);
        float mx = fmaxf(e0, fmaxf(e1, e2));
        float x0 = __expf(e0 - mx), x1 = __expf(e1 - mx), x2 = __expf(e2 - mx);
        float inv = 1.f / (x0 + x1 + x2 + 1e-16f);
        alpha[0][tid][0] = x0 * inv; alpha[0][tid][1] = x1 * inv;
        alpha[0][tid][2] = x2 * inv;
      }
      __syncthreads();
      const float a0 = alpha[0][head][0], a1 = alpha[0][head][1], a2 = alpha[0][head][2];
      v.x = a0 * v.x + a1 * v1.x + a2 * v2.x;
      v.y = a0 * v.y + a1 * v1.y + a2 * v2.y;
      v.z = a0 * v.z + a1 * v1.z + a2 * v2.z;
      v.w = a0 * v.w + a1 * v1.w + a2 * v2.w;
    }
    if constexpr (!MEAN) {
      const float4 bv = *(const float4*)(bias + c4);
      ushort4 o;
      o.x = f2bf(v.x + bv.x); o.y = f2bf(v.y + bv.y);
      o.z = f2bf(v.z + bv.z); o.w = f2bf(v.w + bv.w);
      const int mt = 2048 + (idx >> 4), r = idx & 15;
      *(ushort4*)((u16*)out +
                  (((size_t)(mt * 32 + kb) * 64 + q * 16 + r) * 8 + j0)) = o;
    } else {
      __shared__ float redA[1024];
      *(float4*)(&redA[c4]) = v;
      __syncthreads();
      float* of = (float*)out;
      of[(size_t)node * 256 + tid] =
          0.25f * (redA[tid] + redA[tid + 256] + redA[tid + 512] + redA[tid + 768]) +
          bias[tid];
    }
  }
}

// ---------------- barrier-free LayerNorm(256) + partial pooling -------------
__global__ __launch_bounds__(256) void ln_pool_kernel(
    const float* __restrict__ xf, const float* __restrict__ g,
    const float* __restrict__ bb, float* __restrict__ part) {
  const int tid = threadIdx.x;
  const int wave = tid >> 6, lane = tid & 63;
  const int node0 = blockIdx.x * 64 + wave * 16;
  const float4 g4 = *(const float4*)(g + lane * 4);
  const float4 b4 = *(const float4*)(bb + lane * 4);
  float4 acc = {0.f, 0.f, 0.f, 0.f};
  for (int i = 0; i < 16; ++i) {
    const float4 v = *(const float4*)(xf + (size_t)(node0 + i) * 256 + lane * 4);
    const float s = wredx(v.x + v.y + v.z + v.w);
    const float q = wredx(v.x * v.x + v.y * v.y + v.z * v.z + v.w * v.w);
    const float mean = s * (1.f / 256.f);
    const float var = q * (1.f / 256.f) - mean * mean;
    const float rstd = rsqrtf(var + 1e-5f);
    acc.x += (v.x - mean) * rstd * g4.x + b4.x;
    acc.y += (v.y - mean) * rstd * g4.y + b4.y;
    acc.z += (v.z - mean) * rstd * g4.z + b4.z;
    acc.w += (v.w - mean) * rstd * g4.w + b4.w;
  }
  *(float4*)(part + (size_t)(blockIdx.x * 4 + wave) * 256 + lane * 4) = acc;
}

__global__ __launch_bounds__(256) void pool2_kernel(const float* __restrict__ part,
                                                    float* __restrict__ out) {
  const int chunk = blockIdx.x;
  const int c = threadIdx.x;
  float s = 0.f;
  for (int i = 0; i < 192; ++i) s += part[(size_t)(chunk * 192 + i) * 256 + c];
  out[chunk * 256 + c] = s * (1.f / 3072.f);
}

// ---------------------------------------------------------------------------
extern "C" void kernel_launch(void* const* d_in, const int* in_sizes, int n_in,
                              void* d_out, int out_size, void* d_ws, size_t ws_size,
                              hipStream_t stream) {
  const float* x_reg[4] = {(const float*)d_in[0], (const float*)d_in[1],
                           (const float*)d_in[2], (const float*)d_in[3]};
  const float* audio = (const float*)d_in[4];
  const float* w_reg[4] = {(const float*)d_in[5], (const float*)d_in[7],
                           (const float*)d_in[9], (const float*)d_in[11]};
  const float* b_reg[4] = {(const float*)d_in[6], (const float*)d_in[8],
                           (const float*)d_in[10], (const float*)d_in[12]};
  const float* w_aud = (const float*)d_in[13];
  const float* b_aud = (const float*)d_in[14];
  const float* Wl[3] = {(const float*)d_in[15], (const float*)d_in[19],
                        (const float*)d_in[23]};
  const float* as_in[3] = {(const float*)d_in[16], (const float*)d_in[20],
                           (const float*)d_in[24]};
  const float* ad_in[3] = {(const float*)d_in[17], (const float*)d_in[21],
                           (const float*)d_in[25]};
  const float* bias_l[3] = {(const float*)d_in[18], (const float*)d_in[22],
                            (const float*)d_in[26]};
  const float* ln_g = (const float*)d_in[27];
  const float* ln_b = (const float*)d_in[28];

  // workspace layout (<200 MiB)
  char* ws = (char*)d_ws;
  u16* h_bf = (u16*)ws;                    // [N,1024] bf16 (96 MiB)
  float* part = (float*)ws;                // ln partials (h dead by then)
  u16* xb = (u16*)(ws + 100663296);        // x buffer: row-major x0, then packed
  float* xf = (float*)xb;                  // layer-2 output [N,256] fp32
  u16* wt = (u16*)(ws + 201326592);        // packed bf16 weights (~6 MiB)

  u16* wtp[5];
  for (int r = 0; r < 5; ++r) wtp[r] = wt + (size_t)r * 131072;
  u16* wt0 = wt + 655360;   // 512 frags
  u16* wt1 = wt + 917504;   // 2048 frags
  u16* wt2 = wt + 1966080;  // 2048 frags

  // 1) pack all weights into MFMA fragment order
  PK pk;
  for (int r = 0; r < 4; ++r) { pk.W[r] = w_reg[r]; pk.P[r] = wtp[r]; pk.KB[r] = 16; pk.NN[r] = 256; }
  pk.W[4] = w_aud; pk.P[4] = wtp[4]; pk.KB[4] = 16; pk.NN[4] = 256;
  pk.W[5] = Wl[0]; pk.P[5] = wt0; pk.KB[5] = 8;  pk.NN[5] = 1024;
  pk.W[6] = Wl[1]; pk.P[6] = wt1; pk.KB[6] = 32; pk.NN[6] = 1024;
  pk.W[7] = Wl[2]; pk.P[7] = wt2; pk.KB[7] = 32; pk.NN[7] = 1024;
  pk.st[0] = 0;
  {
    const int nfr[8] = {256, 256, 256, 256, 256, 512, 2048, 2048};
    int acc = 0;
    for (int e = 0; e < 8; ++e) { acc += nfr[e]; pk.st[e + 1] = acc; }
  }
  pack_kernel<<<pk.st[8] / 4, 256, 0, stream>>>(pk);

  // 2) fused input projections (fp32 in) -> x0 row-major [N,256]
  ProjArgs pa;
  for (int r = 0; r < 4; ++r) { pa.x[r] = x_reg[r]; pa.w[r] = wtp[r]; pa.b[r] = b_reg[r]; }
  pa.x[4] = audio; pa.w[4] = wtp[4]; pa.b[4] = b_aud;
  proj_kernel<<<dim3(2, 384), 256, 0, stream>>>(pa, xb);

  // 3) GAT layer 0: LDS-staged GEMM (row-major x0), agg writes packed x
  gemm_kernel<<<dim3(8, 384), 256, 0, stream>>>(xb, wt0, h_bf, 256, 1024);
  agg_kernel<false><<<24576, 256, 0, stream>>>(h_bf, as_in[0], ad_in[0],
                                               bias_l[0], xb);
  // layers 1,2: barrier-free packed GEMM
  gemm_packed_kernel<<<dim3(8, 384), 256, 0, stream>>>(xb, wt1, h_bf);
  agg_kernel<false><<<24576, 256, 0, stream>>>(h_bf, as_in[1], ad_in[1],
                                               bias_l[1], xb);
  gemm_packed_kernel<<<dim3(8, 384), 256, 0, stream>>>(xb, wt2, h_bf);
  agg_kernel<true><<<24576, 256, 0, stream>>>(h_bf, as_in[2], ad_in[2],
                                              bias_l[2], xf);

  // 4) LayerNorm + chunk pooling -> out [16,256]
  ln_pool_kernel<<<768, 256, 0, stream>>>(xf, ln_g, ln_b, part);
  pool2_kernel<<<16, 256, 0, stream>>>(part, (float*)d_out);
}

// Round 6
// 657.079 us; speedup vs baseline: 1.1270x; 1.1270x over previous
//
#include <hip/hip_runtime.h>

// ---------------------------------------------------------------------------
// MultiModalRelationGraph — R6  (= R4 structure + double-buffered GEMM K-loop)
// - GEMM: 256 thr / 4 waves, 128x128 tile, per-wave 64x64 (4x4 MFMA, 64 AGPR).
//   A staged via global_load_lds(16B) into PING-PONG LDS buffers: prefetch of
//   k+1 issued before compute of k, so the vmcnt drain at the barrier waits on
//   loads already ~300cyc in flight; 1 barrier/iter instead of 2.
//   B pre-packed in MFMA fragment order, global->VGPR (L2-resident; R4).
//   R5 lesson: LDS staging is the reuse amplifier — pure-global operands are
//   L2-BW-bound (0.125 B/FLOP > 56 B/cyc/CU). Keep A in LDS.
// - XCD-aware block swizzle (FETCH ~= A size, R2), XOR LDS swizzle (0
//   conflicts, R2), alphas inside agg (R3), fused proj, barrier-free LN.
// Node layout: region i in [i*8192,(i+1)*8192), node = i*8192 + b*512 + t.
// Audio: 32768 + b*1024 + ta.
// ---------------------------------------------------------------------------

typedef unsigned short u16;
typedef unsigned int u32;
typedef __bf16 bf16x8 __attribute__((ext_vector_type(8)));
typedef float f32x4 __attribute__((ext_vector_type(4)));

#define ASYNC16(gp, lp)                                                        \
  __builtin_amdgcn_global_load_lds(                                            \
      (const __attribute__((address_space(1))) void*)(gp),                     \
      (__attribute__((address_space(3))) void*)(lp), 16, 0, 0)

__device__ __forceinline__ u16 f2bf(float f) {
  union { float f; u32 u; } v; v.f = f;
  u32 u = v.u + 0x7FFFu + ((v.u >> 16) & 1u);  // RNE
  return (u16)(u >> 16);
}
__device__ __forceinline__ float bf2f(u16 x) {
  union { u32 u; float f; } v; v.u = ((u32)x) << 16;
  return v.f;
}
__device__ __forceinline__ float4 load_bf4(const u16* p) {
  ushort4 s = *(const ushort4*)p;
  float4 r; r.x = bf2f(s.x); r.y = bf2f(s.y); r.z = bf2f(s.z); r.w = bf2f(s.w);
  return r;
}
__device__ __forceinline__ float lrelu(float v) { return v > 0.f ? v : 0.2f * v; }
__device__ __forceinline__ float dot4(float4 a, float4 b) {
  return a.x * b.x + a.y * b.y + a.z * b.z + a.w * b.w;
}
__device__ __forceinline__ float wred(float v) {  // lane 0 valid
#pragma unroll
  for (int off = 32; off; off >>= 1) v += __shfl_down(v, off);
  return v;
}
__device__ __forceinline__ float wredx(float v) {  // all lanes valid
#pragma unroll
  for (int off = 32; off; off >>= 1) v += __shfl_xor(v, off);
  return v;
}

// ---------------- weight pack: W [K][N] fp32 -> MFMA B-fragment order -------
struct PK { const float* W[8]; u16* P[8]; int KB[8]; int NN[8]; int st[9]; };
__global__ __launch_bounds__(256) void pack_kernel(PK p) {
  const int f = blockIdx.x * 4 + (threadIdx.x >> 6);
  const int lane = threadIdx.x & 63;
  int e = 0;
  while (f >= p.st[e + 1]) ++e;
  const int local = f - p.st[e];
  const int KB = p.KB[e], N = p.NN[e];
  const int nt = local / KB, kb = local % KB;
  const float* W = p.W[e] + (size_t)(kb * 32 + (lane >> 4) * 8) * N + nt * 16 + (lane & 15);
  u16* dst = p.P[e] + ((size_t)local * 64 + lane) * 8;
  u16 o[8];
#pragma unroll
  for (int j = 0; j < 8; ++j) o[j] = f2bf(W[(size_t)j * N]);
  *(uint4*)dst = *(uint4*)o;
}

// ---------------- layer GEMM: C[M,N]=A[M,K]@W^T; dbuf LDS A, packed B -------
// gridDim.x must be 8 (XCD swizzle: one A row-strip's col-blocks on one XCD).
__global__ __launch_bounds__(256) void gemm_kernel(
    const u16* __restrict__ A, const u16* __restrict__ Bp, u16* __restrict__ C,
    int K, int ldc) {
  __shared__ __align__(16) u16 As[2][128 * 32];  // ping-pong, 8 KB each
  const int KB = K >> 5;
  const int w = blockIdx.y * 8 + blockIdx.x;
  const int xcd = w & 7, m = w >> 3;
  const int blockCol = (m & 7) * 128;
  const int blockRow = ((m >> 3) * 8 + xcd) * 128;
  const int tid = threadIdx.x;
  const int wave = tid >> 6, lane = tid & 63;
  const int wr = (wave >> 1) * 64, wc = (wave & 1) * 64;
  const int lr = lane & 15, lq = lane >> 4;
  const int sRow = wave * 16 + (lane >> 2);
  const int sGc = (lane & 3) ^ ((sRow >> 1) & 3);
  const size_t aOff0 = (size_t)(blockRow + sRow) * K + sGc * 8;
  const size_t aOff1 = aOff0 + (size_t)64 * K;
  const int ldsOff0 = wave * 512;
  const int ldsOff1 = 2048 + wave * 512;

  const u16* Bn[4];
#pragma unroll
  for (int ni = 0; ni < 4; ++ni)
    Bn[ni] = Bp + ((size_t)(((blockCol + wc) >> 4) + ni) * KB) * 512 + lane * 8;

  f32x4 acc[4][4] = {};

  // prologue: stage k-block 0 into buffer 0
  ASYNC16(A + aOff0, As[0] + ldsOff0);
  ASYNC16(A + aOff1, As[0] + ldsOff1);
  __syncthreads();

  for (int kb = 0; kb < KB; ++kb) {
    const u16* cur = As[kb & 1];
    u16* nxt = As[(kb & 1) ^ 1];
    if (kb + 1 < KB) {  // prefetch next tile; drain overlaps this iter's compute
      const size_t k1 = (size_t)(kb + 1) * 32;
      ASYNC16(A + aOff0 + k1, nxt + ldsOff0);
      ASYNC16(A + aOff1 + k1, nxt + ldsOff1);
    }
    bf16x8 bfr[4];
#pragma unroll
    for (int ni = 0; ni < 4; ++ni)
      bfr[ni] = *(const bf16x8*)(Bn[ni] + (size_t)kb * 512);
    bf16x8 af[4];
#pragma unroll
    for (int mi = 0; mi < 4; ++mi) {
      const int R = wr + mi * 16 + lr;
      const int cp = lq ^ ((R >> 1) & 3);
      af[mi] = *(const bf16x8*)(cur + R * 32 + cp * 8);
    }
#pragma unroll
    for (int mi = 0; mi < 4; ++mi)
#pragma unroll
      for (int ni = 0; ni < 4; ++ni)
        acc[mi][ni] = __builtin_amdgcn_mfma_f32_16x16x32_bf16(af[mi], bfr[ni],
                                                              acc[mi][ni], 0, 0, 0);
    __syncthreads();  // waits: reads of cur done + prefetch into nxt landed
  }
  // C/D layout: col=lane&15, row=(lane>>4)*4+reg [m89/m91]
#pragma unroll
  for (int mi = 0; mi < 4; ++mi)
#pragma unroll
    for (int ni = 0; ni < 4; ++ni) {
      const int col = blockCol + wc + ni * 16 + lr;
#pragma unroll
      for (int r = 0; r < 4; ++r) {
        const int row = blockRow + wr + mi * 16 + lq * 4 + r;
        C[(size_t)row * ldc + col] = f2bf(acc[mi][ni][r]);
      }
    }
}

// ---------------- fused input projection (fp32 A in-register cvt) -----------
struct ProjArgs { const float* x[5]; const u16* w[5]; const float* b[5]; };
__global__ __launch_bounds__(256) void proj_kernel(ProjArgs pa,
                                                   u16* __restrict__ C) {
  __shared__ __align__(16) u16 As[128 * 32];
  const int blockRow = blockIdx.y * 128, blockCol = blockIdx.x * 128;
  const int reg = blockRow >= 32768 ? 4 : (blockRow >> 13);
  const int regBase = reg == 4 ? 32768 : reg * 8192;
  const float* Af = pa.x[reg] + (size_t)(blockRow - regBase) * 512;
  const u16* Bp = pa.w[reg];
  const int tid = threadIdx.x;
  const int wave = tid >> 6, lane = tid & 63;
  const int wr = (wave >> 1) * 64, wc = (wave & 1) * 64;
  const int lr = lane & 15, lq = lane >> 4;
  const int rr = tid >> 2;
  const int cphys = tid & 3;
  const int sGc = cphys ^ ((tid >> 3) & 3);

  const u16* Bn[4];
#pragma unroll
  for (int ni = 0; ni < 4; ++ni)
    Bn[ni] = Bp + ((size_t)(((blockCol + wc) >> 4) + ni) * 16) * 512 + lane * 8;

  f32x4 acc[4][4] = {};

  for (int k0 = 0; k0 < 512; k0 += 32) {
    __syncthreads();
    bf16x8 bfr[4];
#pragma unroll
    for (int ni = 0; ni < 4; ++ni)
      bfr[ni] = *(const bf16x8*)(Bn[ni] + (size_t)k0 * 16);
#pragma unroll
    for (int i = 0; i < 2; ++i) {
      const int row = i * 64 + rr;
      const float* ap = Af + (size_t)row * 512 + k0 + sGc * 8;
      float4 f0 = *(const float4*)(ap);
      float4 f1 = *(const float4*)(ap + 4);
      uint4 pk;
      pk.x = (u32)f2bf(f0.x) | ((u32)f2bf(f0.y) << 16);
      pk.y = (u32)f2bf(f0.z) | ((u32)f2bf(f0.w) << 16);
      pk.z = (u32)f2bf(f1.x) | ((u32)f2bf(f1.y) << 16);
      pk.w = (u32)f2bf(f1.z) | ((u32)f2bf(f1.w) << 16);
      *(uint4*)(&As[row * 32 + cphys * 8]) = pk;
    }
    __syncthreads();
    bf16x8 af[4];
#pragma unroll
    for (int mi = 0; mi < 4; ++mi) {
      const int R = wr + mi * 16 + lr;
      const int cp = lq ^ ((R >> 1) & 3);
      af[mi] = *(const bf16x8*)(&As[R * 32 + cp * 8]);
    }
#pragma unroll
    for (int mi = 0; mi < 4; ++mi)
#pragma unroll
      for (int ni = 0; ni < 4; ++ni)
        acc[mi][ni] = __builtin_amdgcn_mfma_f32_16x16x32_bf16(af[mi], bfr[ni],
                                                              acc[mi][ni], 0, 0, 0);
  }
  const float* bias = pa.b[reg];
#pragma unroll
  for (int mi = 0; mi < 4; ++mi)
#pragma unroll
    for (int ni = 0; ni < 4; ++ni) {
      const int col = blockCol + wc + ni * 16 + lr;
      const float bv = bias[col];
#pragma unroll
      for (int r = 0; r < 4; ++r) {
        const int row = blockRow + wr + mi * 16 + lq * 4 + r;
        C[(size_t)row * 256 + col] = f2bf(acc[mi][ni][r] + bv);
      }
    }
}

// ---------------- fused aggregation: region (bid<8192) + audio --------------
template <bool MEAN>
__global__ __launch_bounds__(256) void agg_kernel(
    const u16* __restrict__ h, const float* __restrict__ a_s,
    const float* __restrict__ a_d, const float* __restrict__ bias,
    void* __restrict__ out) {
  const int tid = threadIdx.x;
  const int head = tid >> 6, lane = tid & 63;
  const int c4 = tid * 4;
  const float4 sa = *(const float4*)(a_s + c4);
  const float4 da = *(const float4*)(a_d + c4);
  __shared__ float asL[4][4], adL[4][4], apL[4][4];
  __shared__ float alpha[4][4][5];

  if (blockIdx.x < 8192) {
    const int bt = blockIdx.x;
    const int t = bt & 511;
    const bool hasPrev = t > 0;
    float4 hv[4], hp[4];
#pragma unroll
    for (int r = 0; r < 4; ++r)
      hv[r] = load_bf4(h + (size_t)(r * 8192 + bt) * 1024 + c4);
    if (hasPrev) {
#pragma unroll
      for (int r = 0; r < 4; ++r)
        hp[r] = load_bf4(h + (size_t)(r * 8192 + bt - 1) * 1024 + c4);
    }
#pragma unroll
    for (int r = 0; r < 4; ++r) {
      float ss = wred(dot4(hv[r], sa));
      float dd = wred(dot4(hv[r], da));
      float sp = hasPrev ? wred(dot4(hp[r], sa)) : 0.f;
      if (lane == 0) { asL[r][head] = ss; adL[r][head] = dd; apL[r][head] = sp; }
    }
    __syncthreads();
    if (tid < 16) {
      const int j = tid >> 2, hh = tid & 3;
      const float ad = adL[j][hh];
      float e[5];
#pragma unroll
      for (int r = 0; r < 4; ++r) e[r] = lrelu(asL[r][hh] + ad);
      int cnt = 4;
      if (hasPrev) { e[4] = lrelu(apL[j][hh] + ad); cnt = 5; }
      float mx = e[0];
      for (int k = 1; k < cnt; ++k) mx = fmaxf(mx, e[k]);
      float s = 0.f, ex[5];
      for (int k = 0; k < cnt; ++k) { ex[k] = __expf(e[k] - mx); s += ex[k]; }
      const float inv = 1.f / (s + 1e-16f);
#pragma unroll
      for (int k = 0; k < 5; ++k) alpha[j][hh][k] = (k < cnt) ? ex[k] * inv : 0.f;
    }
    __syncthreads();
    if constexpr (!MEAN) {
      const float4 bv = *(const float4*)(bias + c4);
      u16* ob = (u16*)out;
#pragma unroll
      for (int j = 0; j < 4; ++j) {
        const float* al = &alpha[j][head][0];
        float4 acc;
        acc.x = al[0] * hv[0].x + al[1] * hv[1].x + al[2] * hv[2].x + al[3] * hv[3].x;
        acc.y = al[0] * hv[0].y + al[1] * hv[1].y + al[2] * hv[2].y + al[3] * hv[3].y;
        acc.z = al[0] * hv[0].z + al[1] * hv[1].z + al[2] * hv[2].z + al[3] * hv[3].z;
        acc.w = al[0] * hv[0].w + al[1] * hv[1].w + al[2] * hv[2].w + al[3] * hv[3].w;
        if (hasPrev) {
          const float a4 = al[4];
          acc.x += a4 * hp[j].x; acc.y += a4 * hp[j].y;
          acc.z += a4 * hp[j].z; acc.w += a4 * hp[j].w;
        }
        ushort4 o;
        o.x = f2bf(acc.x + bv.x); o.y = f2bf(acc.y + bv.y);
        o.z = f2bf(acc.z + bv.z); o.w = f2bf(acc.w + bv.w);
        *(ushort4*)(ob + (size_t)(j * 8192 + bt) * 1024 + c4) = o;
      }
    } else {
      __shared__ float red[4][1024];
#pragma unroll
      for (int j = 0; j < 4; ++j) {
        const float* al = &alpha[j][head][0];
        float4 acc;
        acc.x = al[0] * hv[0].x + al[1] * hv[1].x + al[2] * hv[2].x + al[3] * hv[3].x;
        acc.y = al[0] * hv[0].y + al[1] * hv[1].y + al[2] * hv[2].y + al[3] * hv[3].y;
        acc.z = al[0] * hv[0].z + al[1] * hv[1].z + al[2] * hv[2].z + al[3] * hv[3].z;
        acc.w = al[0] * hv[0].w + al[1] * hv[1].w + al[2] * hv[2].w + al[3] * hv[3].w;
        if (hasPrev) {
          const float a4 = al[4];
          acc.x += a4 * hp[j].x; acc.y += a4 * hp[j].y;
          acc.z += a4 * hp[j].z; acc.w += a4 * hp[j].w;
        }
        *(float4*)(&red[j][c4]) = acc;
      }
      __syncthreads();
      const float bb = bias[tid];
      float* of = (float*)out;
#pragma unroll
      for (int j = 0; j < 4; ++j)
        of[(size_t)(j * 8192 + bt) * 256 + tid] =
            0.25f * (red[j][tid] + red[j][tid + 256] + red[j][tid + 512] +
                     red[j][tid + 768]) + bb;
    }
  } else {
    const int idx = blockIdx.x - 8192;  // b*1024 + ta
    const int ta = idx & 1023;
    const int node = 32768 + idx;
    const bool even = ((ta & 1) == 0);
    float4 v = load_bf4(h + (size_t)node * 1024 + c4);
    if (even) {
      const int b = idx >> 10;
      const int tt = ta >> 1;
      const int le = 8192 + b * 512 + tt;
      const int re = 16384 + b * 512 + tt;
      float4 v1 = load_bf4(h + (size_t)le * 1024 + c4);
      float4 v2 = load_bf4(h + (size_t)re * 1024 + c4);
      float s0 = wred(dot4(v, sa));
      float s1 = wred(dot4(v1, sa));
      float s2 = wred(dot4(v2, sa));
      float d0 = wred(dot4(v, da));
      if (lane == 0) {
        asL[0][head] = s0; asL[1][head] = s1; asL[2][head] = s2; adL[0][head] = d0;
      }
      __syncthreads();
      if (tid < 4) {
        const float ad = adL[0][tid];
        float e0 = lrelu(asL[0][tid] + ad);
        float e1 = lrelu(asL[1][tid] + ad);
        float e2 = lrelu(asL[2][tid] + ad);
        float mx = fmaxf(e0, fmaxf(e1, e2));
        float x0 = __expf(e0 - mx), x1 = __expf(e1 - mx), x2 = __expf(e2 - mx);
        float inv = 1.f / (x0 + x1 + x2 + 1e-16f);
        alpha[0][tid][0] = x0 * inv; alpha[0][tid][1] = x1 * inv;
        alpha[0][tid][2] = x2 * inv;
      }
      __syncthreads();
      const float a0 = alpha[0][head][0], a1 = alpha[0][head][1], a2 = alpha[0][head][2];
      v.x = a0 * v.x + a1 * v1.x + a2 * v2.x;
      v.y = a0 * v.y + a1 * v1.y + a2 * v2.y;
      v.z = a0 * v.z + a1 * v1.z + a2 * v2.z;
      v.w = a0 * v.w + a1 * v1.w + a2 * v2.w;
    }
    if constexpr (!MEAN) {
      const float4 bv = *(const float4*)(bias + c4);
      ushort4 o;
      o.x = f2bf(v.x + bv.x); o.y = f2bf(v.y + bv.y);
      o.z = f2bf(v.z + bv.z); o.w = f2bf(v.w + bv.w);
      *(ushort4*)((u16*)out + (size_t)node * 1024 + c4) = o;
    } else {
      __shared__ float redA[1024];
      *(float4*)(&redA[c4]) = v;
      __syncthreads();
      float* of = (float*)out;
      of[(size_t)node * 256 + tid] =
          0.25f * (redA[tid] + redA[tid + 256] + redA[tid + 512] + redA[tid + 768]) +
          bias[tid];
    }
  }
}

// ---------------- barrier-free LayerNorm(256) + partial pooling -------------
__global__ __launch_bounds__(256) void ln_pool_kernel(
    const float* __restrict__ xf, const float* __restrict__ g,
    const float* __restrict__ bb, float* __restrict__ part) {
  const int tid = threadIdx.x;
  const int wave = tid >> 6, lane = tid & 63;
  const int node0 = blockIdx.x * 64 + wave * 16;
  const float4 g4 = *(const float4*)(g + lane * 4);
  const float4 b4 = *(const float4*)(bb + lane * 4);
  float4 acc = {0.f, 0.f, 0.f, 0.f};
  for (int i = 0; i < 16; ++i) {
    const float4 v = *(const float4*)(xf + (size_t)(node0 + i) * 256 + lane * 4);
    const float s = wredx(v.x + v.y + v.z + v.w);
    const float q = wredx(v.x * v.x + v.y * v.y + v.z * v.z + v.w * v.w);
    const float mean = s * (1.f / 256.f);
    const float var = q * (1.f / 256.f) - mean * mean;
    const float rstd = rsqrtf(var + 1e-5f);
    acc.x += (v.x - mean) * rstd * g4.x + b4.x;
    acc.y += (v.y - mean) * rstd * g4.y + b4.y;
    acc.z += (v.z - mean) * rstd * g4.z + b4.z;
    acc.w += (v.w - mean) * rstd * g4.w + b4.w;
  }
  *(float4*)(part + (size_t)(blockIdx.x * 4 + wave) * 256 + lane * 4) = acc;
}

__global__ __launch_bounds__(256) void pool2_kernel(const float* __restrict__ part,
                                                    float* __restrict__ out) {
  const int chunk = blockIdx.x;
  const int c = threadIdx.x;
  float s = 0.f;
  for (int i = 0; i < 192; ++i) s += part[(size_t)(chunk * 192 + i) * 256 + c];
  out[chunk * 256 + c] = s * (1.f / 3072.f);
}

// ---------------------------------------------------------------------------
extern "C" void kernel_launch(void* const* d_in, const int* in_sizes, int n_in,
                              void* d_out, int out_size, void* d_ws, size_t ws_size,
                              hipStream_t stream) {
  const float* x_reg[4] = {(const float*)d_in[0], (const float*)d_in[1],
                           (const float*)d_in[2], (const float*)d_in[3]};
  const float* audio = (const float*)d_in[4];
  const float* w_reg[4] = {(const float*)d_in[5], (const float*)d_in[7],
                           (const float*)d_in[9], (const float*)d_in[11]};
  const float* b_reg[4] = {(const float*)d_in[6], (const float*)d_in[8],
                           (const float*)d_in[10], (const float*)d_in[12]};
  const float* w_aud = (const float*)d_in[13];
  const float* b_aud = (const float*)d_in[14];
  const float* Wl[3] = {(const float*)d_in[15], (const float*)d_in[19],
                        (const float*)d_in[23]};
  const float* as_in[3] = {(const float*)d_in[16], (const float*)d_in[20],
                           (const float*)d_in[24]};
  const float* ad_in[3] = {(const float*)d_in[17], (const float*)d_in[21],
                           (const float*)d_in[25]};
  const float* bias_l[3] = {(const float*)d_in[18], (const float*)d_in[22],
                            (const float*)d_in[26]};
  const float* ln_g = (const float*)d_in[27];
  const float* ln_b = (const float*)d_in[28];

  // workspace layout (<200 MiB)
  char* ws = (char*)d_ws;
  u16* h_bf = (u16*)ws;                    // [N,1024] bf16 (96 MiB)
  float* part = (float*)ws;                // ln partials (h dead by then)
  u16* xb = (u16*)(ws + 100663296);        // [N,1024] bf16 x buffer
  float* xf = (float*)xb;                  // layer-2 output [N,256] fp32
  u16* wt = (u16*)(ws + 201326592);        // packed bf16 weights (~6 MiB)

  u16* wtp[5];
  for (int r = 0; r < 5; ++r) wtp[r] = wt + (size_t)r * 131072;
  u16* wt0 = wt + 655360;   // 512 frags
  u16* wt1 = wt + 917504;   // 2048 frags
  u16* wt2 = wt + 1966080;  // 2048 frags

  // 1) pack all weights into MFMA fragment order
  PK pk;
  for (int r = 0; r < 4; ++r) { pk.W[r] = w_reg[r]; pk.P[r] = wtp[r]; pk.KB[r] = 16; pk.NN[r] = 256; }
  pk.W[4] = w_aud; pk.P[4] = wtp[4]; pk.KB[4] = 16; pk.NN[4] = 256;
  pk.W[5] = Wl[0]; pk.P[5] = wt0; pk.KB[5] = 8;  pk.NN[5] = 1024;
  pk.W[6] = Wl[1]; pk.P[6] = wt1; pk.KB[6] = 32; pk.NN[6] = 1024;
  pk.W[7] = Wl[2]; pk.P[7] = wt2; pk.KB[7] = 32; pk.NN[7] = 1024;
  pk.st[0] = 0;
  {
    const int nfr[8] = {256, 256, 256, 256, 256, 512, 2048, 2048};
    int acc = 0;
    for (int e = 0; e < 8; ++e) { acc += nfr[e]; pk.st[e + 1] = acc; }
  }
  pack_kernel<<<pk.st[8] / 4, 256, 0, stream>>>(pk);

  // 2) fused input projections (fp32 in, bf16 out) -> x0 [N,256]
  ProjArgs pa;
  for (int r = 0; r < 4; ++r) { pa.x[r] = x_reg[r]; pa.w[r] = wtp[r]; pa.b[r] = b_reg[r]; }
  pa.x[4] = audio; pa.w[4] = wtp[4]; pa.b[4] = b_aud;
  proj_kernel<<<dim3(2, 384), 256, 0, stream>>>(pa, xb);

  // 3) three GAT layers: dbuf gemm -> fused agg (alphas in-kernel)
  const u16* wl[3] = {wt0, wt1, wt2};
  const int Kl[3] = {256, 1024, 1024};
  for (int l = 0; l < 3; ++l) {
    gemm_kernel<<<dim3(8, 384), 256, 0, stream>>>(xb, wl[l], h_bf, Kl[l], 1024);
    if (l < 2)
      agg_kernel<false><<<24576, 256, 0, stream>>>(h_bf, as_in[l], ad_in[l],
                                                   bias_l[l], xb);
    else
      agg_kernel<true><<<24576, 256, 0, stream>>>(h_bf, as_in[l], ad_in[l],
                                                  bias_l[l], xf);
  }

  // 4) LayerNorm + chunk pooling -> out [16,256]
  ln_pool_kernel<<<768, 256, 0, stream>>>(xf, ln_g, ln_b, part);
  pool2_kernel<<<16, 256, 0, stream>>>(part, (float*)d_out);
}

// Round 7
// 637.719 us; speedup vs baseline: 1.1612x; 1.0304x over previous
//
#include <hip/hip_runtime.h>

// ---------------------------------------------------------------------------
// MultiModalRelationGraph — R7  (= R6 + BK=64 double-buffered GEMM K-loop)
// - GEMM: 256 thr / 4 waves, 128x128 tile, per-wave 64x64 (4x4 MFMA, 64 AGPR).
//   Ping-pong LDS buffers of 16 KB (BK=64): 4 global_load_lds(16B) per
//   prefetch, 32 MFMA per barrier (2x R6), 16 barriers for K=1024.
//   Prefetch issued ~256cyc before consumption -> drain fully hidden.
//   B pre-packed in MFMA fragment order, global->VGPR (L2-resident; R4).
//   R5 lesson: LDS staging is the reuse amplifier — keep A in LDS.
//   Occupancy: 2x16KB LDS x 3 blocks/CU = 96 KB < 160 KB (VGPR-limited, ok).
// - XCD-aware block swizzle (R2), XOR LDS swizzle (0 conflicts, R2),
//   alphas inside agg (R3), fused proj, barrier-free LN.
// Node layout: region i in [i*8192,(i+1)*8192), node = i*8192 + b*512 + t.
// Audio: 32768 + b*1024 + ta.
// ---------------------------------------------------------------------------

typedef unsigned short u16;
typedef unsigned int u32;
typedef __bf16 bf16x8 __attribute__((ext_vector_type(8)));
typedef float f32x4 __attribute__((ext_vector_type(4)));

#define ASYNC16(gp, lp)                                                        \
  __builtin_amdgcn_global_load_lds(                                            \
      (const __attribute__((address_space(1))) void*)(gp),                     \
      (__attribute__((address_space(3))) void*)(lp), 16, 0, 0)

__device__ __forceinline__ u16 f2bf(float f) {
  union { float f; u32 u; } v; v.f = f;
  u32 u = v.u + 0x7FFFu + ((v.u >> 16) & 1u);  // RNE
  return (u16)(u >> 16);
}
__device__ __forceinline__ float bf2f(u16 x) {
  union { u32 u; float f; } v; v.u = ((u32)x) << 16;
  return v.f;
}
__device__ __forceinline__ float4 load_bf4(const u16* p) {
  ushort4 s = *(const ushort4*)p;
  float4 r; r.x = bf2f(s.x); r.y = bf2f(s.y); r.z = bf2f(s.z); r.w = bf2f(s.w);
  return r;
}
__device__ __forceinline__ float lrelu(float v) { return v > 0.f ? v : 0.2f * v; }
__device__ __forceinline__ float dot4(float4 a, float4 b) {
  return a.x * b.x + a.y * b.y + a.z * b.z + a.w * b.w;
}
__device__ __forceinline__ float wred(float v) {  // lane 0 valid
#pragma unroll
  for (int off = 32; off; off >>= 1) v += __shfl_down(v, off);
  return v;
}
__device__ __forceinline__ float wredx(float v) {  // all lanes valid
#pragma unroll
  for (int off = 32; off; off >>= 1) v += __shfl_xor(v, off);
  return v;
}

// ---------------- weight pack: W [K][N] fp32 -> MFMA B-fragment order -------
struct PK { const float* W[8]; u16* P[8]; int KB[8]; int NN[8]; int st[9]; };
__global__ __launch_bounds__(256) void pack_kernel(PK p) {
  const int f = blockIdx.x * 4 + (threadIdx.x >> 6);
  const int lane = threadIdx.x & 63;
  int e = 0;
  while (f >= p.st[e + 1]) ++e;
  const int local = f - p.st[e];
  const int KB = p.KB[e], N = p.NN[e];
  const int nt = local / KB, kb = local % KB;
  const float* W = p.W[e] + (size_t)(kb * 32 + (lane >> 4) * 8) * N + nt * 16 + (lane & 15);
  u16* dst = p.P[e] + ((size_t)local * 64 + lane) * 8;
  u16 o[8];
#pragma unroll
  for (int j = 0; j < 8; ++j) o[j] = f2bf(W[(size_t)j * N]);
  *(uint4*)dst = *(uint4*)o;
}

// ---------------- layer GEMM: C[M,N]=A[M,K]@W^T; BK=64 dbuf LDS A ----------
// gridDim.x must be 8 (XCD swizzle). K must be a multiple of 64.
__global__ __launch_bounds__(256) void gemm_kernel(
    const u16* __restrict__ A, const u16* __restrict__ Bp, u16* __restrict__ C,
    int K, int ldc) {
  __shared__ __align__(16) u16 As[2][2][128 * 32];  // [buf][k-half], 16 KB/buf
  const int KB = K >> 5;        // 32-wide k-blocks (B fragment granule)
  const int KB2 = K >> 6;       // 64-wide buffer granule
  const int w = blockIdx.y * 8 + blockIdx.x;
  const int xcd = w & 7, m = w >> 3;
  const int blockCol = (m & 7) * 128;
  const int blockRow = ((m >> 3) * 8 + xcd) * 128;
  const int tid = threadIdx.x;
  const int wave = tid >> 6, lane = tid & 63;
  const int wr = (wave >> 1) * 64, wc = (wave & 1) * 64;
  const int lr = lane & 15, lq = lane >> 4;
  const int sRow = wave * 16 + (lane >> 2);
  const int sGc = (lane & 3) ^ ((sRow >> 1) & 3);
  const size_t aOff0 = (size_t)(blockRow + sRow) * K + sGc * 8;
  const size_t aOff1 = aOff0 + (size_t)64 * K;
  const int ldsOff0 = wave * 512;
  const int ldsOff1 = 2048 + wave * 512;

  const u16* Bn[4];
#pragma unroll
  for (int ni = 0; ni < 4; ++ni)
    Bn[ni] = Bp + ((size_t)(((blockCol + wc) >> 4) + ni) * KB) * 512 + lane * 8;

  f32x4 acc[4][4] = {};

  // prologue: stage 64-wide k-block 0 into buffer 0 (both halves)
#pragma unroll
  for (int h = 0; h < 2; ++h) {
    ASYNC16(A + aOff0 + h * 32, As[0][h] + ldsOff0);
    ASYNC16(A + aOff1 + h * 32, As[0][h] + ldsOff1);
  }
  __syncthreads();

  for (int kb2 = 0; kb2 < KB2; ++kb2) {
    const int cb = kb2 & 1;
    if (kb2 + 1 < KB2) {  // prefetch next 64-wide block into alternate buffer
      const size_t k1 = (size_t)(kb2 + 1) * 64;
#pragma unroll
      for (int h = 0; h < 2; ++h) {
        ASYNC16(A + aOff0 + k1 + h * 32, As[cb ^ 1][h] + ldsOff0);
        ASYNC16(A + aOff1 + k1 + h * 32, As[cb ^ 1][h] + ldsOff1);
      }
    }
#pragma unroll
    for (int h = 0; h < 2; ++h) {
      const int kb = kb2 * 2 + h;
      const u16* cur = As[cb][h];
      bf16x8 bfr[4];
#pragma unroll
      for (int ni = 0; ni < 4; ++ni)
        bfr[ni] = *(const bf16x8*)(Bn[ni] + (size_t)kb * 512);
      bf16x8 af[4];
#pragma unroll
      for (int mi = 0; mi < 4; ++mi) {
        const int R = wr + mi * 16 + lr;
        const int cp = lq ^ ((R >> 1) & 3);
        af[mi] = *(const bf16x8*)(cur + R * 32 + cp * 8);
      }
#pragma unroll
      for (int mi = 0; mi < 4; ++mi)
#pragma unroll
        for (int ni = 0; ni < 4; ++ni)
          acc[mi][ni] = __builtin_amdgcn_mfma_f32_16x16x32_bf16(af[mi], bfr[ni],
                                                                acc[mi][ni], 0, 0, 0);
    }
    __syncthreads();  // reads of cur done + prefetch landed
  }
  // C/D layout: col=lane&15, row=(lane>>4)*4+reg [m89/m91]
#pragma unroll
  for (int mi = 0; mi < 4; ++mi)
#pragma unroll
    for (int ni = 0; ni < 4; ++ni) {
      const int col = blockCol + wc + ni * 16 + lr;
#pragma unroll
      for (int r = 0; r < 4; ++r) {
        const int row = blockRow + wr + mi * 16 + lq * 4 + r;
        C[(size_t)row * ldc + col] = f2bf(acc[mi][ni][r]);
      }
    }
}

// ---------------- fused input projection (fp32 A in-register cvt) -----------
struct ProjArgs { const float* x[5]; const u16* w[5]; const float* b[5]; };
__global__ __launch_bounds__(256) void proj_kernel(ProjArgs pa,
                                                   u16* __restrict__ C) {
  __shared__ __align__(16) u16 As[128 * 32];
  const int blockRow = blockIdx.y * 128, blockCol = blockIdx.x * 128;
  const int reg = blockRow >= 32768 ? 4 : (blockRow >> 13);
  const int regBase = reg == 4 ? 32768 : reg * 8192;
  const float* Af = pa.x[reg] + (size_t)(blockRow - regBase) * 512;
  const u16* Bp = pa.w[reg];
  const int tid = threadIdx.x;
  const int wave = tid >> 6, lane = tid & 63;
  const int wr = (wave >> 1) * 64, wc = (wave & 1) * 64;
  const int lr = lane & 15, lq = lane >> 4;
  const int rr = tid >> 2;
  const int cphys = tid & 3;
  const int sGc = cphys ^ ((tid >> 3) & 3);

  const u16* Bn[4];
#pragma unroll
  for (int ni = 0; ni < 4; ++ni)
    Bn[ni] = Bp + ((size_t)(((blockCol + wc) >> 4) + ni) * 16) * 512 + lane * 8;

  f32x4 acc[4][4] = {};

  for (int k0 = 0; k0 < 512; k0 += 32) {
    __syncthreads();
    bf16x8 bfr[4];
#pragma unroll
    for (int ni = 0; ni < 4; ++ni)
      bfr[ni] = *(const bf16x8*)(Bn[ni] + (size_t)k0 * 16);
#pragma unroll
    for (int i = 0; i < 2; ++i) {
      const int row = i * 64 + rr;
      const float* ap = Af + (size_t)row * 512 + k0 + sGc * 8;
      float4 f0 = *(const float4*)(ap);
      float4 f1 = *(const float4*)(ap + 4);
      uint4 pk;
      pk.x = (u32)f2bf(f0.x) | ((u32)f2bf(f0.y) << 16);
      pk.y = (u32)f2bf(f0.z) | ((u32)f2bf(f0.w) << 16);
      pk.z = (u32)f2bf(f1.x) | ((u32)f2bf(f1.y) << 16);
      pk.w = (u32)f2bf(f1.z) | ((u32)f2bf(f1.w) << 16);
      *(uint4*)(&As[row * 32 + cphys * 8]) = pk;
    }
    __syncthreads();
    bf16x8 af[4];
#pragma unroll
    for (int mi = 0; mi < 4; ++mi) {
      const int R = wr + mi * 16 + lr;
      const int cp = lq ^ ((R >> 1) & 3);
      af[mi] = *(const bf16x8*)(&As[R * 32 + cp * 8]);
    }
#pragma unroll
    for (int mi = 0; mi < 4; ++mi)
#pragma unroll
      for (int ni = 0; ni < 4; ++ni)
        acc[mi][ni] = __builtin_amdgcn_mfma_f32_16x16x32_bf16(af[mi], bfr[ni],
                                                              acc[mi][ni], 0, 0, 0);
  }
  const float* bias = pa.b[reg];
#pragma unroll
  for (int mi = 0; mi < 4; ++mi)
#pragma unroll
    for (int ni = 0; ni < 4; ++ni) {
      const int col = blockCol + wc + ni * 16 + lr;
      const float bv = bias[col];
#pragma unroll
      for (int r = 0; r < 4; ++r) {
        const int row = blockRow + wr + mi * 16 + lq * 4 + r;
        C[(size_t)row * 256 + col] = f2bf(acc[mi][ni][r] + bv);
      }
    }
}

// ---------------- fused aggregation: region (bid<8192) + audio --------------
template <bool MEAN>
__global__ __launch_bounds__(256) void agg_kernel(
    const u16* __restrict__ h, const float* __restrict__ a_s,
    const float* __restrict__ a_d, const float* __restrict__ bias,
    void* __restrict__ out) {
  const int tid = threadIdx.x;
  const int head = tid >> 6, lane = tid & 63;
  const int c4 = tid * 4;
  const float4 sa = *(const float4*)(a_s + c4);
  const float4 da = *(const float4*)(a_d + c4);
  __shared__ float asL[4][4], adL[4][4], apL[4][4];
  __shared__ float alpha[4][4][5];

  if (blockIdx.x < 8192) {
    const int bt = blockIdx.x;
    const int t = bt & 511;
    const bool hasPrev = t > 0;
    float4 hv[4], hp[4];
#pragma unroll
    for (int r = 0; r < 4; ++r)
      hv[r] = load_bf4(h + (size_t)(r * 8192 + bt) * 1024 + c4);
    if (hasPrev) {
#pragma unroll
      for (int r = 0; r < 4; ++r)
        hp[r] = load_bf4(h + (size_t)(r * 8192 + bt - 1) * 1024 + c4);
    }
#pragma unroll
    for (int r = 0; r < 4; ++r) {
      float ss = wred(dot4(hv[r], sa));
      float dd = wred(dot4(hv[r], da));
      float sp = hasPrev ? wred(dot4(hp[r], sa)) : 0.f;
      if (lane == 0) { asL[r][head] = ss; adL[r][head] = dd; apL[r][head] = sp; }
    }
    __syncthreads();
    if (tid < 16) {
      const int j = tid >> 2, hh = tid & 3;
      const float ad = adL[j][hh];
      float e[5];
#pragma unroll
      for (int r = 0; r < 4; ++r) e[r] = lrelu(asL[r][hh] + ad);
      int cnt = 4;
      if (hasPrev) { e[4] = lrelu(apL[j][hh] + ad); cnt = 5; }
      float mx = e[0];
      for (int k = 1; k < cnt; ++k) mx = fmaxf(mx, e[k]);
      float s = 0.f, ex[5];
      for (int k = 0; k < cnt; ++k) { ex[k] = __expf(e[k] - mx); s += ex[k]; }
      const float inv = 1.f / (s + 1e-16f);
#pragma unroll
      for (int k = 0; k < 5; ++k) alpha[j][hh][k] = (k < cnt) ? ex[k] * inv : 0.f;
    }
    __syncthreads();
    if constexpr (!MEAN) {
      const float4 bv = *(const float4*)(bias + c4);
      u16* ob = (u16*)out;
#pragma unroll
      for (int j = 0; j < 4; ++j) {
        const float* al = &alpha[j][head][0];
        float4 acc;
        acc.x = al[0] * hv[0].x + al[1] * hv[1].x + al[2] * hv[2].x + al[3] * hv[3].x;
        acc.y = al[0] * hv[0].y + al[1] * hv[1].y + al[2] * hv[2].y + al[3] * hv[3].y;
        acc.z = al[0] * hv[0].z + al[1] * hv[1].z + al[2] * hv[2].z + al[3] * hv[3].z;
        acc.w = al[0] * hv[0].w + al[1] * hv[1].w + al[2] * hv[2].w + al[3] * hv[3].w;
        if (hasPrev) {
          const float a4 = al[4];
          acc.x += a4 * hp[j].x; acc.y += a4 * hp[j].y;
          acc.z += a4 * hp[j].z; acc.w += a4 * hp[j].w;
        }
        ushort4 o;
        o.x = f2bf(acc.x + bv.x); o.y = f2bf(acc.y + bv.y);
        o.z = f2bf(acc.z + bv.z); o.w = f2bf(acc.w + bv.w);
        *(ushort4*)(ob + (size_t)(j * 8192 + bt) * 1024 + c4) = o;
      }
    } else {
      __shared__ float red[4][1024];
#pragma unroll
      for (int j = 0; j < 4; ++j) {
        const float* al = &alpha[j][head][0];
        float4 acc;
        acc.x = al[0] * hv[0].x + al[1] * hv[1].x + al[2] * hv[2].x + al[3] * hv[3].x;
        acc.y = al[0] * hv[0].y + al[1] * hv[1].y + al[2] * hv[2].y + al[3] * hv[3].y;
        acc.z = al[0] * hv[0].z + al[1] * hv[1].z + al[2] * hv[2].z + al[3] * hv[3].z;
        acc.w = al[0] * hv[0].w + al[1] * hv[1].w + al[2] * hv[2].w + al[3] * hv[3].w;
        if (hasPrev) {
          const float a4 = al[4];
          acc.x += a4 * hp[j].x; acc.y += a4 * hp[j].y;
          acc.z += a4 * hp[j].z; acc.w += a4 * hp[j].w;
        }
        *(float4*)(&red[j][c4]) = acc;
      }
      __syncthreads();
      const float bb = bias[tid];
      float* of = (float*)out;
#pragma unroll
      for (int j = 0; j < 4; ++j)
        of[(size_t)(j * 8192 + bt) * 256 + tid] =
            0.25f * (red[j][tid] + red[j][tid + 256] + red[j][tid + 512] +
                     red[j][tid + 768]) + bb;
    }
  } else {
    const int idx = blockIdx.x - 8192;  // b*1024 + ta
    const int ta = idx & 1023;
    const int node = 32768 + idx;
    const bool even = ((ta & 1) == 0);
    float4 v = load_bf4(h + (size_t)node * 1024 + c4);
    if (even) {
      const int b = idx >> 10;
      const int tt = ta >> 1;
      const int le = 8192 + b * 512 + tt;
      const int re = 16384 + b * 512 + tt;
      float4 v1 = load_bf4(h + (size_t)le * 1024 + c4);
      float4 v2 = load_bf4(h + (size_t)re * 1024 + c4);
      float s0 = wred(dot4(v, sa));
      float s1 = wred(dot4(v1, sa));
      float s2 = wred(dot4(v2, sa));
      float d0 = wred(dot4(v, da));
      if (lane == 0) {
        asL[0][head] = s0; asL[1][head] = s1; asL[2][head] = s2; adL[0][head] = d0;
      }
      __syncthreads();
      if (tid < 4) {
        const float ad = adL[0][tid];
        float e0 = lrelu(asL[0][tid] + ad);
        float e1 = lrelu(asL[1][tid] + ad);
        float e2 = lrelu(asL[2][tid] + ad);
        float mx = fmaxf(e0, fmaxf(e1, e2));
        float x0 = __expf(e0 - mx), x1 = __expf(e1 - mx), x2 = __expf(e2 - mx);
        float inv = 1.f / (x0 + x1 + x2 + 1e-16f);
        alpha[0][tid][0] = x0 * inv; alpha[0][tid][1] = x1 * inv;
        alpha[0][tid][2] = x2 * inv;
      }
      __syncthreads();
      const float a0 = alpha[0][head][0], a1 = alpha[0][head][1], a2 = alpha[0][head][2];
      v.x = a0 * v.x + a1 * v1.x + a2 * v2.x;
      v.y = a0 * v.y + a1 * v1.y + a2 * v2.y;
      v.z = a0 * v.z + a1 * v1.z + a2 * v2.z;
      v.w = a0 * v.w + a1 * v1.w + a2 * v2.w;
    }
    if constexpr (!MEAN) {
      const float4 bv = *(const float4*)(bias + c4);
      ushort4 o;
      o.x = f2bf(v.x + bv.x); o.y = f2bf(v.y + bv.y);
      o.z = f2bf(v.z + bv.z); o.w = f2bf(v.w + bv.w);
      *(ushort4*)((u16*)out + (size_t)node * 1024 + c4) = o;
    } else {
      __shared__ float redA[1024];
      *(float4*)(&redA[c4]) = v;
      __syncthreads();
      float* of = (float*)out;
      of[(size_t)node * 256 + tid] =
          0.25f * (redA[tid] + redA[tid + 256] + redA[tid + 512] + redA[tid + 768]) +
          bias[tid];
    }
  }
}

// ---------------- barrier-free LayerNorm(256) + partial pooling -------------
__global__ __launch_bounds__(256) void ln_pool_kernel(
    const float* __restrict__ xf, const float* __restrict__ g,
    const float* __restrict__ bb, float* __restrict__ part) {
  const int tid = threadIdx.x;
  const int wave = tid >> 6, lane = tid & 63;
  const int node0 = blockIdx.x * 64 + wave * 16;
  const float4 g4 = *(const float4*)(g + lane * 4);
  const float4 b4 = *(const float4*)(bb + lane * 4);
  float4 acc = {0.f, 0.f, 0.f, 0.f};
  for (int i = 0; i < 16; ++i) {
    const float4 v = *(const float4*)(xf + (size_t)(node0 + i) * 256 + lane * 4);
    const float s = wredx(v.x + v.y + v.z + v.w);
    const float q = wredx(v.x * v.x + v.y * v.y + v.z * v.z + v.w * v.w);
    const float mean = s * (1.f / 256.f);
    const float var = q * (1.f / 256.f) - mean * mean;
    const float rstd = rsqrtf(var + 1e-5f);
    acc.x += (v.x - mean) * rstd * g4.x + b4.x;
    acc.y += (v.y - mean) * rstd * g4.y + b4.y;
    acc.z += (v.z - mean) * rstd * g4.z + b4.z;
    acc.w += (v.w - mean) * rstd * g4.w + b4.w;
  }
  *(float4*)(part + (size_t)(blockIdx.x * 4 + wave) * 256 + lane * 4) = acc;
}

__global__ __launch_bounds__(256) void pool2_kernel(const float* __restrict__ part,
                                                    float* __restrict__ out) {
  const int chunk = blockIdx.x;
  const int c = threadIdx.x;
  float s = 0.f;
  for (int i = 0; i < 192; ++i) s += part[(size_t)(chunk * 192 + i) * 256 + c];
  out[chunk * 256 + c] = s * (1.f / 3072.f);
}

// ---------------------------------------------------------------------------
extern "C" void kernel_launch(void* const* d_in, const int* in_sizes, int n_in,
                              void* d_out, int out_size, void* d_ws, size_t ws_size,
                              hipStream_t stream) {
  const float* x_reg[4] = {(const float*)d_in[0], (const float*)d_in[1],
                           (const float*)d_in[2], (const float*)d_in[3]};
  const float* audio = (const float*)d_in[4];
  const float* w_reg[4] = {(const float*)d_in[5], (const float*)d_in[7],
                           (const float*)d_in[9], (const float*)d_in[11]};
  const float* b_reg[4] = {(const float*)d_in[6], (const float*)d_in[8],
                           (const float*)d_in[10], (const float*)d_in[12]};
  const float* w_aud = (const float*)d_in[13];
  const float* b_aud = (const float*)d_in[14];
  const float* Wl[3] = {(const float*)d_in[15], (const float*)d_in[19],
                        (const float*)d_in[23]};
  const float* as_in[3] = {(const float*)d_in[16], (const float*)d_in[20],
                           (const float*)d_in[24]};
  const float* ad_in[3] = {(const float*)d_in[17], (const float*)d_in[21],
                           (const float*)d_in[25]};
  const float* bias_l[3] = {(const float*)d_in[18], (const float*)d_in[22],
                            (const float*)d_in[26]};
  const float* ln_g = (const float*)d_in[27];
  const float* ln_b = (const float*)d_in[28];

  // workspace layout (<200 MiB)
  char* ws = (char*)d_ws;
  u16* h_bf = (u16*)ws;                    // [N,1024] bf16 (96 MiB)
  float* part = (float*)ws;                // ln partials (h dead by then)
  u16* xb = (u16*)(ws + 100663296);        // [N,1024] bf16 x buffer
  float* xf = (float*)xb;                  // layer-2 output [N,256] fp32
  u16* wt = (u16*)(ws + 201326592);        // packed bf16 weights (~6 MiB)

  u16* wtp[5];
  for (int r = 0; r < 5; ++r) wtp[r] = wt + (size_t)r * 131072;
  u16* wt0 = wt + 655360;   // 512 frags
  u16* wt1 = wt + 917504;   // 2048 frags
  u16* wt2 = wt + 1966080;  // 2048 frags

  // 1) pack all weights into MFMA fragment order
  PK pk;
  for (int r = 0; r < 4; ++r) { pk.W[r] = w_reg[r]; pk.P[r] = wtp[r]; pk.KB[r] = 16; pk.NN[r] = 256; }
  pk.W[4] = w_aud; pk.P[4] = wtp[4]; pk.KB[4] = 16; pk.NN[4] = 256;
  pk.W[5] = Wl[0]; pk.P[5] = wt0; pk.KB[5] = 8;  pk.NN[5] = 1024;
  pk.W[6] = Wl[1]; pk.P[6] = wt1; pk.KB[6] = 32; pk.NN[6] = 1024;
  pk.W[7] = Wl[2]; pk.P[7] = wt2; pk.KB[7] = 32; pk.NN[7] = 1024;
  pk.st[0] = 0;
  {
    const int nfr[8] = {256, 256, 256, 256, 256, 512, 2048, 2048};
    int acc = 0;
    for (int e = 0; e < 8; ++e) { acc += nfr[e]; pk.st[e + 1] = acc; }
  }
  pack_kernel<<<pk.st[8] / 4, 256, 0, stream>>>(pk);

  // 2) fused input projections (fp32 in, bf16 out) -> x0 [N,256]
  ProjArgs pa;
  for (int r = 0; r < 4; ++r) { pa.x[r] = x_reg[r]; pa.w[r] = wtp[r]; pa.b[r] = b_reg[r]; }
  pa.x[4] = audio; pa.w[4] = wtp[4]; pa.b[4] = b_aud;
  proj_kernel<<<dim3(2, 384), 256, 0, stream>>>(pa, xb);

  // 3) three GAT layers: BK=64 dbuf gemm -> fused agg (alphas in-kernel)
  const u16* wl[3] = {wt0, wt1, wt2};
  const int Kl[3] = {256, 1024, 1024};
  for (int l = 0; l < 3; ++l) {
    gemm_kernel<<<dim3(8, 384), 256, 0, stream>>>(xb, wl[l], h_bf, Kl[l], 1024);
    if (l < 2)
      agg_kernel<false><<<24576, 256, 0, stream>>>(h_bf, as_in[l], ad_in[l],
                                                   bias_l[l], xb);
    else
      agg_kernel<true><<<24576, 256, 0, stream>>>(h_bf, as_in[l], ad_in[l],
                                                  bias_l[l], xf);
  }

  // 4) LayerNorm + chunk pooling -> out [16,256]
  ln_pool_kernel<<<768, 256, 0, stream>>>(xf, ln_g, ln_b, part);
  pool2_kernel<<<16, 256, 0, stream>>>(part, (float*)d_out);
}